// Round 1
// baseline (96.538 us; speedup 1.0000x reference)
//
#include <hip/hip_runtime.h>

// Quantize x to nearest codeword on the fixed grid g_j = j - 7.5, j in [0,16),
// replicating the reference's fp32 score arithmetic bit-exactly:
//   s_j = 2.0f * fl(x * g_j) - g_j^2 ; argmax with first-max tie-break.
// (Closed-form round(x+7.5) would mismatch near boundaries due to fp32
//  rounding of x*g_j — a single flipped index fails the absmax threshold.)

__device__ __forceinline__ void quant1(float x, float& val, float& idxf) {
    // j = 0: g = -7.5, n = 56.25
    float best = 2.0f * (x * -7.5f) - 56.25f;
    int bi = 0;
#pragma unroll
    for (int j = 1; j < 16; ++j) {
        const float g = (float)j - 7.5f;     // compile-time constant
        const float n = g * g;               // exact in fp32 (x.25 values)
        float s = 2.0f * (x * g) - n;        // fma(2, x*g, -n) is bit-identical
        bool gt = s > best;                  // strict > keeps FIRST max (ties -> lower j)
        best = gt ? s : best;
        bi = gt ? j : bi;
    }
    val = (float)bi - 7.5f;                  // grid[bi], exact
    idxf = (float)bi;                        // idx output compared as float
}

__global__ __launch_bounds__(256) void quant4_kernel(const float4* __restrict__ x4,
                                                     float4* __restrict__ val4,
                                                     float4* __restrict__ idx4,
                                                     int nquads) {
    int i = blockIdx.x * blockDim.x + threadIdx.x;
    if (i >= nquads) return;
    float4 x = x4[i];
    float4 v, f;
    quant1(x.x, v.x, f.x);
    quant1(x.y, v.y, f.y);
    quant1(x.z, v.z, f.z);
    quant1(x.w, v.w, f.w);
    val4[i] = v;
    idx4[i] = f;
}

__global__ void quant_tail_kernel(const float* __restrict__ x,
                                  float* __restrict__ val,
                                  float* __restrict__ idxf,
                                  int start, int n) {
    int i = start + blockIdx.x * blockDim.x + threadIdx.x;
    if (i >= n) return;
    float v, f;
    quant1(x[i], v, f);
    val[i] = v;
    idxf[i] = f;
}

extern "C" void kernel_launch(void* const* d_in, const int* in_sizes, int n_in,
                              void* d_out, int out_size, void* d_ws, size_t ws_size,
                              hipStream_t stream) {
    const float* X = (const float*)d_in[0];
    float* out = (float*)d_out;
    const int n = in_sizes[0];          // 8,388,608
    float* vals = out;                  // first n floats: quantized values
    float* idxf = out + n;              // next n floats: indices (as float)

    const int nquads = n / 4;
    const int block = 256;
    const int grid = (nquads + block - 1) / block;   // 8192 blocks at n=8.4M
    quant4_kernel<<<grid, block, 0, stream>>>(
        (const float4*)X, (float4*)vals, (float4*)idxf, nquads);

    const int rem = n - nquads * 4;
    if (rem > 0) {
        quant_tail_kernel<<<1, 64, 0, stream>>>(X, vals, idxf, nquads * 4, n);
    }
}